// Round 3
// baseline (648.983 us; speedup 1.0000x reference)
//
#include <hip/hip_runtime.h>
#include <stdint.h>

#define NB 8
#define LP 2048
#define LQS 2048
#define HD 1024

typedef _Float16 h16;
typedef _Float16 half8 __attribute__((ext_vector_type(8)));
typedef _Float16 half4 __attribute__((ext_vector_type(4)));
typedef float f32x4 __attribute__((ext_vector_type(4)));

__device__ __forceinline__ void gload16(const void* g, void* l) {
    __builtin_amdgcn_global_load_lds(
        (const __attribute__((address_space(1))) void*)g,
        (__attribute__((address_space(3))) void*)l, 16, 0, 0);
}

// ---------------- split cast f32 -> f16 hi + f16 lo ----------------
__global__ __launch_bounds__(256) void cast_split(const float* __restrict__ src,
                                                  h16* __restrict__ hi,
                                                  h16* __restrict__ lo, long n) {
    long stride = (long)gridDim.x * 256 * 4;
    for (long i = ((long)blockIdx.x * 256 + threadIdx.x) * 4; i < n; i += stride) {
        f32x4 v = *(const f32x4*)(src + i);
        half4 h, l;
#pragma unroll
        for (int j = 0; j < 4; ++j) {
            h16 hh = (h16)v[j];
            h[j] = hh;
            l[j] = (h16)(v[j] - (float)hh);
        }
        *(half4*)(hi + i) = h;
        *(half4*)(lo + i) = l;
    }
}

// ---------------- V transpose: VT[b][h][q] = Qhi[b][q][h] ----------------
__global__ __launch_bounds__(256) void transpose_v(const h16* __restrict__ Q16,
                                                   h16* __restrict__ VT) {
    int b = blockIdx.z, q0 = blockIdx.y * 64, h0 = blockIdx.x * 64;
    __shared__ h16 tile[64][72];  // 144B row stride (multiple of 16B)
    const h16* src = Q16 + ((size_t)b * LQS + q0) * HD + h0;
    int t = threadIdx.x;
    for (int c = t; c < 512; c += 256) {
        int row = c >> 3, col = (c & 7) * 8;
        *(half8*)&tile[row][col] = *(const half8*)(src + (size_t)row * HD + col);
    }
    __syncthreads();
    h16* dst = VT + ((size_t)b * HD + h0) * LQS + q0;
    for (int c = t; c < 512; c += 256) {
        int hh = c >> 3, q8 = (c & 7) * 8;
        half8 v;
#pragma unroll
        for (int j = 0; j < 8; ++j) v[j] = tile[q8 + j][hh];
        *(half8*)(dst + (size_t)hh * LQS + q8) = v;
    }
}

// ---------------- 128x128 f16 GEMM core: acc += A * B^T ----------------
// LDS [128][64] f16, 16B chunks XOR-swizzled: slot j holds global chunk j^(row&7)
__device__ __forceinline__ void gemm128(const h16* __restrict__ A0, int lda,
                                        const h16* __restrict__ B0, int ldb,
                                        int Kdim, f32x4 acc[4][4],
                                        h16* ldsA, h16* ldsB) {
    const int t = threadIdx.x;
    const int lane = t & 63, wave = t >> 6;
    const int wr = wave >> 1, wc = wave & 1;
    const int fr = lane & 15, fq = lane >> 4;

    for (int kt = 0; kt < Kdim; kt += 64) {
        __syncthreads();
#pragma unroll
        for (int i = 0; i < 4; ++i) {
            int c = i * 256 + t;
            int row = c >> 3, j = c & 7;
            int sc = j ^ (row & 7);  // pre-swizzled global source, linear LDS dest
            gload16(A0 + (size_t)row * lda + kt + sc * 8,
                    ldsA + (size_t)(i * 256 + wave * 64) * 8);
            gload16(B0 + (size_t)row * ldb + kt + sc * 8,
                    ldsB + (size_t)(i * 256 + wave * 64) * 8);
        }
        asm volatile("s_waitcnt vmcnt(0)" ::: "memory");
        __syncthreads();
#pragma unroll
        for (int kk = 0; kk < 2; ++kk) {
            half8 av[4], bv[4];
#pragma unroll
            for (int m = 0; m < 4; ++m) {
                int row = wr * 64 + m * 16 + fr;
                int ch = (kk * 4 + fq) ^ (row & 7);
                av[m] = *(const half8*)(ldsA + row * 64 + ch * 8);
            }
#pragma unroll
            for (int n = 0; n < 4; ++n) {
                int row = wc * 64 + n * 16 + fr;
                int ch = (kk * 4 + fq) ^ (row & 7);
                bv[n] = *(const half8*)(ldsB + row * 64 + ch * 8);
            }
#pragma unroll
            for (int m = 0; m < 4; ++m)
#pragma unroll
                for (int n = 0; n < 4; ++n)
                    acc[m][n] = __builtin_amdgcn_mfma_f32_16x16x32_f16(av[m], bv[n], acc[m][n], 0, 0, 0);
        }
    }
}

#define ACC_INIT(acc) \
    f32x4 acc[4][4];  \
    _Pragma("unroll") for (int m_ = 0; m_ < 4; ++m_) _Pragma("unroll") for (int n_ = 0; n_ < 4; ++n_) acc[m_][n_] = (f32x4){0.f, 0.f, 0.f, 0.f};

// ---------------- K1: trans_q = Q*W^T + b (3-pass split), split-store ----------------
__global__ __launch_bounds__(256) void k_transq(const h16* __restrict__ Qhi,
                                                const h16* __restrict__ Qlo,
                                                const h16* __restrict__ Whi,
                                                const h16* __restrict__ Wlo,
                                                const float* __restrict__ bias,
                                                const int* __restrict__ seq,
                                                h16* __restrict__ Khi,
                                                h16* __restrict__ Klo) {
    int nt = blockIdx.x, mt = blockIdx.y;
    int b = mt >> 4;
    int q0 = (mt & 15) * 128;
    if (q0 >= seq[b]) return;
    __shared__ h16 ldsA[128 * 64], ldsB[128 * 64];
    ACC_INIT(acc);
    size_t aoff = (size_t)mt * 128 * HD;
    const h16* Bh = Whi + (size_t)nt * 128 * HD;
    const h16* Bl = Wlo + (size_t)nt * 128 * HD;
    gemm128(Qhi + aoff, HD, Bh, HD, HD, acc, ldsA, ldsB);
    gemm128(Qhi + aoff, HD, Bl, HD, HD, acc, ldsA, ldsB);
    gemm128(Qlo + aoff, HD, Bh, HD, HD, acc, ldsA, ldsB);
    int lane = threadIdx.x & 63, wave = threadIdx.x >> 6;
    int wr = wave >> 1, wc = wave & 1, fr = lane & 15, fq = lane >> 4;
    size_t rowbase = (size_t)mt * 128;
#pragma unroll
    for (int m = 0; m < 4; ++m)
#pragma unroll
        for (int n = 0; n < 4; ++n) {
            int col = nt * 128 + wc * 64 + n * 16 + fr;
            float bv = bias[col];
#pragma unroll
            for (int j = 0; j < 4; ++j) {
                int row = wr * 64 + m * 16 + fq * 4 + j;
                float tv = acc[m][n][j] + bv;
                h16 th = (h16)tv;
                size_t idx = (rowbase + row) * HD + col;
                Khi[idx] = th;
                Klo[idx] = (h16)(tv - (float)th);
            }
        }
}

// ---------------- K2: S = P * K^T (3-pass split), f32 out ----------------
// blockIdx.z = batch within chunk; b0 = first batch of chunk
__global__ __launch_bounds__(256) void k_scores(const h16* __restrict__ Phi,
                                                const h16* __restrict__ Plo,
                                                const h16* __restrict__ Khi,
                                                const h16* __restrict__ Klo,
                                                const int* __restrict__ seq,
                                                float* __restrict__ S, int b0) {
    int qt = blockIdx.x, pt = blockIdx.y, lb = blockIdx.z;
    int b = b0 + lb;
    if (qt * 128 >= seq[b]) return;
    __shared__ h16 ldsA[128 * 64], ldsB[128 * 64];
    ACC_INIT(acc);
    size_t aoff = ((size_t)b * LP + pt * 128) * HD;
    size_t boff = ((size_t)b * LQS + qt * 128) * HD;
    gemm128(Phi + aoff, HD, Khi + boff, HD, HD, acc, ldsA, ldsB);
    gemm128(Phi + aoff, HD, Klo + boff, HD, HD, acc, ldsA, ldsB);
    gemm128(Plo + aoff, HD, Khi + boff, HD, HD, acc, ldsA, ldsB);
    int lane = threadIdx.x & 63, wave = threadIdx.x >> 6;
    int wr = wave >> 1, wc = wave & 1, fr = lane & 15, fq = lane >> 4;
    float* C = S + ((size_t)lb * LP + pt * 128) * LQS + qt * 128;
#pragma unroll
    for (int m = 0; m < 4; ++m)
#pragma unroll
        for (int n = 0; n < 4; ++n)
#pragma unroll
            for (int j = 0; j < 4; ++j) {
                int row = wr * 64 + m * 16 + fq * 4 + j;
                int col = wc * 64 + n * 16 + fr;
                C[(size_t)row * LQS + col] = acc[m][n][j];
            }
}

// ---------------- K3: softmax (reference mask/renorm semantics), PA f16 in-place ----------------
__global__ __launch_bounds__(256) void softmax_k(float* __restrict__ S,
                                                 const int* __restrict__ seq, int b0) {
    int wid = threadIdx.x >> 6, lane = threadIdx.x & 63;
    int r = blockIdx.x * 4 + wid;   // row within chunk [0, cb*LP)
    int b = b0 + (r >> 11);
    int L = seq[b];
    const float* Srow = S + (size_t)r * LQS;
    h16* Prow = (h16*)(S + (size_t)r * LQS);  // in-place: f16 writes trail f32 reads
    float m = -INFINITY;
    for (int i = lane; i < L; i += 64) m = fmaxf(m, Srow[i]);
#pragma unroll
    for (int off = 32; off; off >>= 1) m = fmaxf(m, __shfl_xor(m, off));
    float M = (L < LQS) ? fmaxf(m, 0.f) : m;
    float s = 0.f;
    for (int i = lane; i < L; i += 64) s += expf(Srow[i] - M);
#pragma unroll
    for (int off = 32; off; off >>= 1) s += __shfl_xor(s, off);
    float corr = (L < LQS) ? (float)(LQS - L) * expf(-M) : 0.f;
    float denom = s + 1e-13f * (s + corr);
    float inv = 1.f / denom;
    int Lpad = (L + 63) & ~63;
    for (int i = lane; i < L; i += 64) {
        float e = expf(Srow[i] - M) * inv;   // read (byte 4i) strictly leads write (byte 2i)
        Prow[i] = (h16)e;
    }
    for (int i = L + lane; i < Lpad; i += 64) Prow[i] = (h16)0.f;
}

// ---------------- K4: out = PA * VT^T ----------------
__global__ __launch_bounds__(256) void k_pv(const h16* __restrict__ PA,
                                            const h16* __restrict__ VT,
                                            const int* __restrict__ seq,
                                            float* __restrict__ out, int b0) {
    int ht = blockIdx.x, pt = blockIdx.y, lb = blockIdx.z;
    int b = b0 + lb;
    int L = seq[b];
    int Lpad = (L + 63) & ~63;
    __shared__ h16 ldsA[128 * 64], ldsB[128 * 64];
    ACC_INIT(acc);
    const h16* A0 = PA + ((size_t)lb * LP + pt * 128) * (2 * LQS);  // PA rows inside f32 S rows
    const h16* B0 = VT + ((size_t)b * HD + ht * 128) * LQS;
    gemm128(A0, 2 * LQS, B0, LQS, Lpad, acc, ldsA, ldsB);
    int lane = threadIdx.x & 63, wave = threadIdx.x >> 6;
    int wr = wave >> 1, wc = wave & 1, fr = lane & 15, fq = lane >> 4;
    float* C = out + ((size_t)b * LP + pt * 128) * HD + ht * 128;
#pragma unroll
    for (int m = 0; m < 4; ++m)
#pragma unroll
        for (int n = 0; n < 4; ++n)
#pragma unroll
            for (int j = 0; j < 4; ++j) {
                int row = wr * 64 + m * 16 + fq * 4 + j;
                int col = wc * 64 + n * 16 + fr;
                C[(size_t)row * HD + col] = acc[m][n][j];
            }
}

extern "C" void kernel_launch(void* const* d_in, const int* in_sizes, int n_in,
                              void* d_out, int out_size, void* d_ws, size_t ws_size,
                              hipStream_t stream) {
    const float* proj_p = (const float*)d_in[0];
    const float* proj_q = (const float*)d_in[1];
    const float* W_t    = (const float*)d_in[2];
    const float* b_t    = (const float*)d_in[3];
    const int*   seq    = (const int*)d_in[4];
    float* out = (float*)d_out;

    // Arena with phase-based reuse (persistent 160 MB + S chunk):
    //  [0,32M):    Qhi  -> (after transpose_v + cast) Phi
    //  [32M,64M):  Qlo  -> (after k_transq) VT
    //  [64M,96M):  Khi
    //  [96M,128M): Klo
    //  [128M,160M):Plo
    //  [160M,...): S chunk (cb batches x 16 MB, f32); Whi/Wlo live at 160M/162M
    //              during cast+k_transq only (dead before S written);
    //              PA = f16 rows written in-place over S rows by softmax_k.
    char* ws = (char*)d_ws;
    const size_t MB = (size_t)1 << 20;
    h16*  Qhi = (h16*)(ws + 0 * MB);
    h16*  Qlo = (h16*)(ws + 32 * MB);
    h16*  Khi = (h16*)(ws + 64 * MB);
    h16*  Klo = (h16*)(ws + 96 * MB);
    h16*  Plo = (h16*)(ws + 128 * MB);
    float* S  = (float*)(ws + 160 * MB);
    h16*  Whi = (h16*)(ws + 160 * MB);  // temporally overlapped with S
    h16*  Wlo = (h16*)(ws + 162 * MB);
    h16*  Phi = Qhi;                    // after transpose_v, Qhi reusable
    h16*  VT  = Qlo;                    // after k_transq, Qlo reusable
    const h16* PA = (const h16*)S;      // f16 rows in-place within f32 S rows
    (void)in_sizes; (void)n_in; (void)out_size;

    // Chunk batches so S fits in ws_size: need 160MB + cb*16MB.
    int cb = 8;
    if (ws_size > 0) {
        size_t avail = (ws_size > 160 * MB) ? (ws_size - 160 * MB) : 0;
        int fit = (int)(avail / (16 * MB));
        cb = (fit >= 8) ? 8 : (fit >= 4) ? 4 : (fit >= 2) ? 2 : 1;
    }

    cast_split<<<1024, 256, 0, stream>>>(W_t, Whi, Wlo, (long)HD * HD);
    cast_split<<<4096, 256, 0, stream>>>(proj_q, Qhi, Qlo, (long)NB * LQS * HD);
    k_transq<<<dim3(HD / 128, NB * LQS / 128), 256, 0, stream>>>(Qhi, Qlo, Whi, Wlo, b_t, seq, Khi, Klo);
    transpose_v<<<dim3(HD / 64, LQS / 64, NB), 256, 0, stream>>>(Qhi, VT);
    cast_split<<<4096, 256, 0, stream>>>(proj_p, Phi, Plo, (long)NB * LP * HD);
    for (int b0 = 0; b0 < NB; b0 += cb) {
        // same-stream ordering serializes chunk c's k_pv before chunk c+1's k_scores
        k_scores<<<dim3(LQS / 128, LP / 128, cb), 256, 0, stream>>>(Phi, Plo, Khi, Klo, seq, S, b0);
        softmax_k<<<cb * LP / 4, 256, 0, stream>>>(S, seq, b0);
        k_pv<<<dim3(HD / 128, LP / 128, cb), 256, 0, stream>>>(PA, VT, seq, out, b0);
    }
}

// Round 5
// 524.510 us; speedup vs baseline: 1.2373x; 1.2373x over previous
//
#include <hip/hip_runtime.h>
#include <stdint.h>

#define NB 8
#define LP 2048
#define LQS 2048
#define HD 1024

typedef _Float16 h16;
typedef _Float16 half8 __attribute__((ext_vector_type(8)));
typedef _Float16 half4 __attribute__((ext_vector_type(4)));
typedef float f32x4 __attribute__((ext_vector_type(4)));

__device__ __forceinline__ void gload16(const void* g, void* l) {
    __builtin_amdgcn_global_load_lds(
        (const __attribute__((address_space(1))) void*)g,
        (__attribute__((address_space(3))) void*)l, 16, 0, 0);
}

// Bijective XCD-aware swizzle (nwg % 8 == 0 on every launch here): each XCD
// gets a contiguous range of flat block ids -> neighboring tiles share L2.
__device__ __forceinline__ void xcd_swz(int& bx, int& by) {
    int gx = gridDim.x;
    int orig = blockIdx.x + gx * blockIdx.y;
    int nw8 = (gx * gridDim.y) >> 3;
    int swz = (orig & 7) * nw8 + (orig >> 3);
    bx = swz % gx;
    by = swz / gx;
}

// ---------------- split cast f32 -> f16 hi + f16 lo ----------------
__global__ __launch_bounds__(256) void cast_split(const float* __restrict__ src,
                                                  h16* __restrict__ hi,
                                                  h16* __restrict__ lo, long n) {
    long stride = (long)gridDim.x * 256 * 4;
    for (long i = ((long)blockIdx.x * 256 + threadIdx.x) * 4; i < n; i += stride) {
        f32x4 v = *(const f32x4*)(src + i);
        half4 h, l;
#pragma unroll
        for (int j = 0; j < 4; ++j) {
            h16 hh = (h16)v[j];
            h[j] = hh;
            l[j] = (h16)(v[j] - (float)hh);
        }
        *(half4*)(hi + i) = h;
        *(half4*)(lo + i) = l;
    }
}

// ---------------- V transpose: VT[b][h][q] = Qhi[b][q][h] ----------------
__global__ __launch_bounds__(256) void transpose_v(const h16* __restrict__ Q16,
                                                   h16* __restrict__ VT) {
    int b = blockIdx.z, q0 = blockIdx.y * 64, h0 = blockIdx.x * 64;
    __shared__ h16 tile[64][72];  // 144B row stride (multiple of 16B)
    const h16* src = Q16 + ((size_t)b * LQS + q0) * HD + h0;
    int t = threadIdx.x;
    for (int c = t; c < 512; c += 256) {
        int row = c >> 3, col = (c & 7) * 8;
        *(half8*)&tile[row][col] = *(const half8*)(src + (size_t)row * HD + col);
    }
    __syncthreads();
    h16* dst = VT + ((size_t)b * HD + h0) * LQS + q0;
    for (int c = t; c < 512; c += 256) {
        int hh = c >> 3, q8 = (c & 7) * 8;
        half8 v;
#pragma unroll
        for (int j = 0; j < 8; ++j) v[j] = tile[q8 + j][hh];
        *(half8*)(dst + (size_t)hh * LQS + q8) = v;
    }
}

// Stage one 128x64 f16 tile into LDS, 16B chunks XOR-swizzled (source-side):
// LDS slot j of row holds global chunk j^(row&7); linear LDS dest for gload_lds.
#define STAGE_TILE(SRC, LD, LDS_)                                   \
    _Pragma("unroll") for (int i_ = 0; i_ < 4; ++i_) {              \
        int c_ = i_ * 256 + t;                                      \
        int row_ = c_ >> 3, j_ = c_ & 7;                            \
        int sc_ = j_ ^ (row_ & 7);                                  \
        gload16((SRC) + (size_t)row_ * (LD) + kt + sc_ * 8,         \
                (LDS_) + (size_t)(i_ * 256 + wave * 64) * 8);       \
    }

// ---------------- fused split-f16 GEMM: acc += Ah*Bh^T + Ah*Bl^T + Al*Bh^T ----
// 96 MFMA per barrier-pair (3x the single-pass rate), 64 KB LDS.
__device__ __forceinline__ void gemm_split(const h16* __restrict__ Ah,
                                           const h16* __restrict__ Al, int lda,
                                           const h16* __restrict__ Bh,
                                           const h16* __restrict__ Bl, int ldb,
                                           int Kdim, f32x4 acc[4][4],
                                           h16* lAh, h16* lAl, h16* lBh, h16* lBl) {
    const int t = threadIdx.x;
    const int lane = t & 63, wave = t >> 6;
    const int wr = wave >> 1, wc = wave & 1;
    const int fr = lane & 15, fq = lane >> 4;

    for (int kt = 0; kt < Kdim; kt += 64) {
        __syncthreads();
        STAGE_TILE(Ah, lda, lAh);
        STAGE_TILE(Al, lda, lAl);
        STAGE_TILE(Bh, ldb, lBh);
        STAGE_TILE(Bl, ldb, lBl);
        asm volatile("s_waitcnt vmcnt(0)" ::: "memory");
        __syncthreads();
#pragma unroll
        for (int kk = 0; kk < 2; ++kk) {
            half8 ah[4], al[4], bh[4], bl[4];
#pragma unroll
            for (int m = 0; m < 4; ++m) {
                int row = wr * 64 + m * 16 + fr;
                int ch = (kk * 4 + fq) ^ (row & 7);
                ah[m] = *(const half8*)(lAh + row * 64 + ch * 8);
                al[m] = *(const half8*)(lAl + row * 64 + ch * 8);
            }
#pragma unroll
            for (int n = 0; n < 4; ++n) {
                int row = wc * 64 + n * 16 + fr;
                int ch = (kk * 4 + fq) ^ (row & 7);
                bh[n] = *(const half8*)(lBh + row * 64 + ch * 8);
                bl[n] = *(const half8*)(lBl + row * 64 + ch * 8);
            }
#pragma unroll
            for (int m = 0; m < 4; ++m)
#pragma unroll
                for (int n = 0; n < 4; ++n) {
                    acc[m][n] = __builtin_amdgcn_mfma_f32_16x16x32_f16(ah[m], bh[n], acc[m][n], 0, 0, 0);
                    acc[m][n] = __builtin_amdgcn_mfma_f32_16x16x32_f16(ah[m], bl[n], acc[m][n], 0, 0, 0);
                    acc[m][n] = __builtin_amdgcn_mfma_f32_16x16x32_f16(al[m], bh[n], acc[m][n], 0, 0, 0);
                }
        }
    }
}

// ---------------- plain 128x128 f16 GEMM (k_pv): acc += A * B^T ----------------
__device__ __forceinline__ void gemm128(const h16* __restrict__ A0, int lda,
                                        const h16* __restrict__ B0, int ldb,
                                        int Kdim, f32x4 acc[4][4],
                                        h16* ldsA, h16* ldsB) {
    const int t = threadIdx.x;
    const int lane = t & 63, wave = t >> 6;
    const int wr = wave >> 1, wc = wave & 1;
    const int fr = lane & 15, fq = lane >> 4;

    for (int kt = 0; kt < Kdim; kt += 64) {
        __syncthreads();
        STAGE_TILE(A0, lda, ldsA);
        STAGE_TILE(B0, ldb, ldsB);
        asm volatile("s_waitcnt vmcnt(0)" ::: "memory");
        __syncthreads();
#pragma unroll
        for (int kk = 0; kk < 2; ++kk) {
            half8 av[4], bv[4];
#pragma unroll
            for (int m = 0; m < 4; ++m) {
                int row = wr * 64 + m * 16 + fr;
                int ch = (kk * 4 + fq) ^ (row & 7);
                av[m] = *(const half8*)(ldsA + row * 64 + ch * 8);
            }
#pragma unroll
            for (int n = 0; n < 4; ++n) {
                int row = wc * 64 + n * 16 + fr;
                int ch = (kk * 4 + fq) ^ (row & 7);
                bv[n] = *(const half8*)(ldsB + row * 64 + ch * 8);
            }
#pragma unroll
            for (int m = 0; m < 4; ++m)
#pragma unroll
                for (int n = 0; n < 4; ++n)
                    acc[m][n] = __builtin_amdgcn_mfma_f32_16x16x32_f16(av[m], bv[n], acc[m][n], 0, 0, 0);
        }
    }
}

#define ACC_INIT(acc) \
    f32x4 acc[4][4];  \
    _Pragma("unroll") for (int m_ = 0; m_ < 4; ++m_) _Pragma("unroll") for (int n_ = 0; n_ < 4; ++n_) acc[m_][n_] = (f32x4){0.f, 0.f, 0.f, 0.f};

// ---------------- K1: trans_q = Q*W^T + b (fused split), split-store ----------------
__global__ __launch_bounds__(256) void k_transq(const h16* __restrict__ Qhi,
                                                const h16* __restrict__ Qlo,
                                                const h16* __restrict__ Whi,
                                                const h16* __restrict__ Wlo,
                                                const float* __restrict__ bias,
                                                const int* __restrict__ seq,
                                                h16* __restrict__ Khi,
                                                h16* __restrict__ Klo) {
    int nt, mt;
    xcd_swz(nt, mt);
    int b = mt >> 4;
    int q0 = (mt & 15) * 128;
    if (q0 >= seq[b]) return;
    __shared__ h16 lAh[128 * 64], lAl[128 * 64], lBh[128 * 64], lBl[128 * 64];
    ACC_INIT(acc);
    size_t aoff = (size_t)mt * 128 * HD;
    size_t boff = (size_t)nt * 128 * HD;
    gemm_split(Qhi + aoff, Qlo + aoff, HD, Whi + boff, Wlo + boff, HD, HD, acc,
               lAh, lAl, lBh, lBl);
    int lane = threadIdx.x & 63, wave = threadIdx.x >> 6;
    int wr = wave >> 1, wc = wave & 1, fr = lane & 15, fq = lane >> 4;
    size_t rowbase = (size_t)mt * 128;
#pragma unroll
    for (int m = 0; m < 4; ++m)
#pragma unroll
        for (int n = 0; n < 4; ++n) {
            int col = nt * 128 + wc * 64 + n * 16 + fr;
            float bv = bias[col];
#pragma unroll
            for (int j = 0; j < 4; ++j) {
                int row = wr * 64 + m * 16 + fq * 4 + j;
                float tv = acc[m][n][j] + bv;
                h16 th = (h16)tv;
                size_t idx = (rowbase + row) * HD + col;
                Khi[idx] = th;
                Klo[idx] = (h16)(tv - (float)th);
            }
        }
}

// ---------------- K2: S = P * K^T (fused split), f32 out ----------------
__global__ __launch_bounds__(256) void k_scores(const h16* __restrict__ Phi,
                                                const h16* __restrict__ Plo,
                                                const h16* __restrict__ Khi,
                                                const h16* __restrict__ Klo,
                                                const int* __restrict__ seq,
                                                float* __restrict__ S, int b0) {
    int qt, pt;
    xcd_swz(qt, pt);
    int lb = blockIdx.z;
    int b = b0 + lb;
    if (qt * 128 >= seq[b]) return;
    __shared__ h16 lAh[128 * 64], lAl[128 * 64], lBh[128 * 64], lBl[128 * 64];
    ACC_INIT(acc);
    size_t aoff = ((size_t)b * LP + pt * 128) * HD;
    size_t boff = ((size_t)b * LQS + qt * 128) * HD;
    gemm_split(Phi + aoff, Plo + aoff, HD, Khi + boff, Klo + boff, HD, HD, acc,
               lAh, lAl, lBh, lBl);
    int lane = threadIdx.x & 63, wave = threadIdx.x >> 6;
    int wr = wave >> 1, wc = wave & 1, fr = lane & 15, fq = lane >> 4;
    float* C = S + ((size_t)lb * LP + pt * 128) * LQS + qt * 128;
#pragma unroll
    for (int m = 0; m < 4; ++m)
#pragma unroll
        for (int n = 0; n < 4; ++n)
#pragma unroll
            for (int j = 0; j < 4; ++j) {
                int row = wr * 64 + m * 16 + fq * 4 + j;
                int col = wc * 64 + n * 16 + fr;
                C[(size_t)row * LQS + col] = acc[m][n][j];
            }
}

// ---------------- K3: softmax (reference mask/renorm semantics), PA f16 in-place ----------------
__global__ __launch_bounds__(256) void softmax_k(float* __restrict__ S,
                                                 const int* __restrict__ seq, int b0) {
    int wid = threadIdx.x >> 6, lane = threadIdx.x & 63;
    int r = blockIdx.x * 4 + wid;   // row within chunk [0, cb*LP)
    int b = b0 + (r >> 11);
    int L = seq[b];
    const float* Srow = S + (size_t)r * LQS;
    h16* Prow = (h16*)(S + (size_t)r * LQS);  // in-place: f16 writes trail f32 reads
    float m = -INFINITY;
    for (int i = lane; i < L; i += 64) m = fmaxf(m, Srow[i]);
#pragma unroll
    for (int off = 32; off; off >>= 1) m = fmaxf(m, __shfl_xor(m, off));
    float M = (L < LQS) ? fmaxf(m, 0.f) : m;
    float s = 0.f;
    for (int i = lane; i < L; i += 64) s += expf(Srow[i] - M);
#pragma unroll
    for (int off = 32; off; off >>= 1) s += __shfl_xor(s, off);
    float corr = (L < LQS) ? (float)(LQS - L) * expf(-M) : 0.f;
    float denom = s + 1e-13f * (s + corr);
    float inv = 1.f / denom;
    int Lpad = (L + 63) & ~63;
    for (int i = lane; i < L; i += 64) {
        float e = expf(Srow[i] - M) * inv;   // read (byte 4i) strictly leads write (byte 2i)
        Prow[i] = (h16)e;
    }
    for (int i = L + lane; i < Lpad; i += 64) Prow[i] = (h16)0.f;
}

// ---------------- K4: out = PA * VT^T ----------------
__global__ __launch_bounds__(256) void k_pv(const h16* __restrict__ PA,
                                            const h16* __restrict__ VT,
                                            const int* __restrict__ seq,
                                            float* __restrict__ out, int b0) {
    int ht, pt;
    xcd_swz(ht, pt);
    int lb = blockIdx.z;
    int b = b0 + lb;
    int L = seq[b];
    int Lpad = (L + 63) & ~63;
    __shared__ h16 ldsA[128 * 64], ldsB[128 * 64];
    ACC_INIT(acc);
    const h16* A0 = PA + ((size_t)lb * LP + pt * 128) * (2 * LQS);  // PA rows inside f32 S rows
    const h16* B0 = VT + ((size_t)b * HD + ht * 128) * LQS;
    gemm128(A0, 2 * LQS, B0, LQS, Lpad, acc, ldsA, ldsB);
    int lane = threadIdx.x & 63, wave = threadIdx.x >> 6;
    int wr = wave >> 1, wc = wave & 1, fr = lane & 15, fq = lane >> 4;
    float* C = out + ((size_t)b * LP + pt * 128) * HD + ht * 128;
#pragma unroll
    for (int m = 0; m < 4; ++m)
#pragma unroll
        for (int n = 0; n < 4; ++n)
#pragma unroll
            for (int j = 0; j < 4; ++j) {
                int row = wr * 64 + m * 16 + fq * 4 + j;
                int col = wc * 64 + n * 16 + fr;
                C[(size_t)row * HD + col] = acc[m][n][j];
            }
}

extern "C" void kernel_launch(void* const* d_in, const int* in_sizes, int n_in,
                              void* d_out, int out_size, void* d_ws, size_t ws_size,
                              hipStream_t stream) {
    const float* proj_p = (const float*)d_in[0];
    const float* proj_q = (const float*)d_in[1];
    const float* W_t    = (const float*)d_in[2];
    const float* b_t    = (const float*)d_in[3];
    const int*   seq    = (const int*)d_in[4];
    float* out = (float*)d_out;

    // Arena with phase-based reuse (persistent 160 MB + S chunk):
    //  [0,32M):    Qhi  -> (after transpose_v + cast) Phi
    //  [32M,64M):  Qlo  -> (after k_transq) VT
    //  [64M,96M):  Khi
    //  [96M,128M): Klo
    //  [128M,160M):Plo
    //  [160M,...): S chunk (cb batches x 16 MB, f32); Whi/Wlo live at 160M/162M
    //              during cast+k_transq only (dead before S written);
    //              PA = f16 rows written in-place over S rows by softmax_k.
    char* ws = (char*)d_ws;
    const size_t MB = (size_t)1 << 20;
    h16*  Qhi = (h16*)(ws + 0 * MB);
    h16*  Qlo = (h16*)(ws + 32 * MB);
    h16*  Khi = (h16*)(ws + 64 * MB);
    h16*  Klo = (h16*)(ws + 96 * MB);
    h16*  Plo = (h16*)(ws + 128 * MB);
    float* S  = (float*)(ws + 160 * MB);
    h16*  Whi = (h16*)(ws + 160 * MB);  // temporally overlapped with S
    h16*  Wlo = (h16*)(ws + 162 * MB);
    h16*  Phi = Qhi;                    // after transpose_v, Qhi reusable
    h16*  VT  = Qlo;                    // after k_transq, Qlo reusable
    const h16* PA = (const h16*)S;      // f16 rows in-place within f32 S rows
    (void)in_sizes; (void)n_in; (void)out_size;

    // Chunk batches so S fits in ws_size: need 160MB + cb*16MB.
    int cb = 8;
    if (ws_size > 0) {
        size_t avail = (ws_size > 160 * MB) ? (ws_size - 160 * MB) : 0;
        int fit = (int)(avail / (16 * MB));
        cb = (fit >= 8) ? 8 : (fit >= 4) ? 4 : (fit >= 2) ? 2 : 1;
    }

    cast_split<<<1024, 256, 0, stream>>>(W_t, Whi, Wlo, (long)HD * HD);
    cast_split<<<4096, 256, 0, stream>>>(proj_q, Qhi, Qlo, (long)NB * LQS * HD);
    k_transq<<<dim3(HD / 128, NB * LQS / 128), 256, 0, stream>>>(Qhi, Qlo, Whi, Wlo, b_t, seq, Khi, Klo);
    transpose_v<<<dim3(HD / 64, LQS / 64, NB), 256, 0, stream>>>(Qhi, VT);
    cast_split<<<4096, 256, 0, stream>>>(proj_p, Phi, Plo, (long)NB * LP * HD);
    for (int b0 = 0; b0 < NB; b0 += cb) {
        // same-stream ordering serializes chunk c's k_pv before chunk c+1's k_scores
        k_scores<<<dim3(LQS / 128, LP / 128, cb), 256, 0, stream>>>(Phi, Plo, Khi, Klo, seq, S, b0);
        softmax_k<<<cb * LP / 4, 256, 0, stream>>>(S, seq, b0);
        k_pv<<<dim3(HD / 128, LP / 128, cb), 256, 0, stream>>>(PA, VT, seq, out, b0);
    }
}

// Round 6
// 520.629 us; speedup vs baseline: 1.2465x; 1.0075x over previous
//
#include <hip/hip_runtime.h>
#include <stdint.h>

#define NB 8
#define LP 2048
#define LQS 2048
#define HD 1024

typedef _Float16 h16;
typedef _Float16 half8 __attribute__((ext_vector_type(8)));
typedef _Float16 half4 __attribute__((ext_vector_type(4)));
typedef float f32x4 __attribute__((ext_vector_type(4)));

__device__ __forceinline__ void gload16(const void* g, void* l) {
    __builtin_amdgcn_global_load_lds(
        (const __attribute__((address_space(1))) void*)g,
        (__attribute__((address_space(3))) void*)l, 16, 0, 0);
}

// Bijective XCD-aware swizzle. NOTE: only valid where it does NOT correlate
// XCD with batch (k_scores/k_pv: XCD -> pt rows, balanced). k_transq must NOT
// use it: there it mapped XCD->batch and seq_len imbalance idled whole XCDs.
__device__ __forceinline__ void xcd_swz(int& bx, int& by) {
    int gx = gridDim.x;
    int orig = blockIdx.x + gx * blockIdx.y;
    int nw8 = (gx * gridDim.y) >> 3;
    int swz = (orig & 7) * nw8 + (orig >> 3);
    bx = swz % gx;
    by = swz / gx;
}

// ---------------- split cast f32 -> f16 hi + f16 lo ----------------
__global__ __launch_bounds__(256) void cast_split(const float* __restrict__ src,
                                                  h16* __restrict__ hi,
                                                  h16* __restrict__ lo, long n) {
    long stride = (long)gridDim.x * 256 * 4;
    for (long i = ((long)blockIdx.x * 256 + threadIdx.x) * 4; i < n; i += stride) {
        f32x4 v = *(const f32x4*)(src + i);
        half4 h, l;
#pragma unroll
        for (int j = 0; j < 4; ++j) {
            h16 hh = (h16)v[j];
            h[j] = hh;
            l[j] = (h16)(v[j] - (float)hh);
        }
        *(half4*)(hi + i) = h;
        *(half4*)(lo + i) = l;
    }
}

// ---------------- V transpose: VT[b][h][q] = Qhi[b][q][h] ----------------
__global__ __launch_bounds__(256) void transpose_v(const h16* __restrict__ Q16,
                                                   h16* __restrict__ VT) {
    int b = blockIdx.z, q0 = blockIdx.y * 64, h0 = blockIdx.x * 64;
    __shared__ h16 tile[64][72];  // 144B row stride (multiple of 16B)
    const h16* src = Q16 + ((size_t)b * LQS + q0) * HD + h0;
    int t = threadIdx.x;
    for (int c = t; c < 512; c += 256) {
        int row = c >> 3, col = (c & 7) * 8;
        *(half8*)&tile[row][col] = *(const half8*)(src + (size_t)row * HD + col);
    }
    __syncthreads();
    h16* dst = VT + ((size_t)b * HD + h0) * LQS + q0;
    for (int c = t; c < 512; c += 256) {
        int hh = c >> 3, q8 = (c & 7) * 8;
        half8 v;
#pragma unroll
        for (int j = 0; j < 8; ++j) v[j] = tile[q8 + j][hh];
        *(half8*)(dst + (size_t)hh * LQS + q8) = v;
    }
}

// Stage one 128x64 f16 tile into LDS, 16B chunks XOR-swizzled (source-side):
// LDS slot j of row holds global chunk j^(row&7); linear LDS dest for gload_lds.
#define STAGE_TILE(SRC, LD, LDS_)                                   \
    _Pragma("unroll") for (int i_ = 0; i_ < 4; ++i_) {              \
        int c_ = i_ * 256 + t;                                      \
        int row_ = c_ >> 3, j_ = c_ & 7;                            \
        int sc_ = j_ ^ (row_ & 7);                                  \
        gload16((SRC) + (size_t)row_ * (LD) + kt + sc_ * 8,         \
                (LDS_) + (size_t)(i_ * 256 + wave * 64) * 8);       \
    }

// ---------------- fused split-f16 GEMM: acc += Ah*Bh^T + Ah*Bl^T + Al*Bh^T ----
// 96 MFMA per barrier-pair (3x the single-pass rate), 64 KB LDS.
__device__ __forceinline__ void gemm_split(const h16* __restrict__ Ah,
                                           const h16* __restrict__ Al, int lda,
                                           const h16* __restrict__ Bh,
                                           const h16* __restrict__ Bl, int ldb,
                                           int Kdim, f32x4 acc[4][4],
                                           h16* lAh, h16* lAl, h16* lBh, h16* lBl) {
    const int t = threadIdx.x;
    const int lane = t & 63, wave = t >> 6;
    const int wr = wave >> 1, wc = wave & 1;
    const int fr = lane & 15, fq = lane >> 4;

    for (int kt = 0; kt < Kdim; kt += 64) {
        __syncthreads();
        STAGE_TILE(Ah, lda, lAh);
        STAGE_TILE(Al, lda, lAl);
        STAGE_TILE(Bh, ldb, lBh);
        STAGE_TILE(Bl, ldb, lBl);
        asm volatile("s_waitcnt vmcnt(0)" ::: "memory");
        __syncthreads();
#pragma unroll
        for (int kk = 0; kk < 2; ++kk) {
            half8 ah[4], al[4], bh[4], bl[4];
#pragma unroll
            for (int m = 0; m < 4; ++m) {
                int row = wr * 64 + m * 16 + fr;
                int ch = (kk * 4 + fq) ^ (row & 7);
                ah[m] = *(const half8*)(lAh + row * 64 + ch * 8);
                al[m] = *(const half8*)(lAl + row * 64 + ch * 8);
            }
#pragma unroll
            for (int n = 0; n < 4; ++n) {
                int row = wc * 64 + n * 16 + fr;
                int ch = (kk * 4 + fq) ^ (row & 7);
                bh[n] = *(const half8*)(lBh + row * 64 + ch * 8);
                bl[n] = *(const half8*)(lBl + row * 64 + ch * 8);
            }
#pragma unroll
            for (int m = 0; m < 4; ++m)
#pragma unroll
                for (int n = 0; n < 4; ++n) {
                    acc[m][n] = __builtin_amdgcn_mfma_f32_16x16x32_f16(ah[m], bh[n], acc[m][n], 0, 0, 0);
                    acc[m][n] = __builtin_amdgcn_mfma_f32_16x16x32_f16(ah[m], bl[n], acc[m][n], 0, 0, 0);
                    acc[m][n] = __builtin_amdgcn_mfma_f32_16x16x32_f16(al[m], bh[n], acc[m][n], 0, 0, 0);
                }
        }
    }
}

// ---------------- plain 128x128 f16 GEMM (k_pv): acc += A * B^T ----------------
__device__ __forceinline__ void gemm128(const h16* __restrict__ A0, int lda,
                                        const h16* __restrict__ B0, int ldb,
                                        int Kdim, f32x4 acc[4][4],
                                        h16* ldsA, h16* ldsB) {
    const int t = threadIdx.x;
    const int lane = t & 63, wave = t >> 6;
    const int wr = wave >> 1, wc = wave & 1;
    const int fr = lane & 15, fq = lane >> 4;

    for (int kt = 0; kt < Kdim; kt += 64) {
        __syncthreads();
        STAGE_TILE(A0, lda, ldsA);
        STAGE_TILE(B0, ldb, ldsB);
        asm volatile("s_waitcnt vmcnt(0)" ::: "memory");
        __syncthreads();
#pragma unroll
        for (int kk = 0; kk < 2; ++kk) {
            half8 av[4], bv[4];
#pragma unroll
            for (int m = 0; m < 4; ++m) {
                int row = wr * 64 + m * 16 + fr;
                int ch = (kk * 4 + fq) ^ (row & 7);
                av[m] = *(const half8*)(ldsA + row * 64 + ch * 8);
            }
#pragma unroll
            for (int n = 0; n < 4; ++n) {
                int row = wc * 64 + n * 16 + fr;
                int ch = (kk * 4 + fq) ^ (row & 7);
                bv[n] = *(const half8*)(ldsB + row * 64 + ch * 8);
            }
#pragma unroll
            for (int m = 0; m < 4; ++m)
#pragma unroll
                for (int n = 0; n < 4; ++n)
                    acc[m][n] = __builtin_amdgcn_mfma_f32_16x16x32_f16(av[m], bv[n], acc[m][n], 0, 0, 0);
        }
    }
}

#define ACC_INIT(acc) \
    f32x4 acc[4][4];  \
    _Pragma("unroll") for (int m_ = 0; m_ < 4; ++m_) _Pragma("unroll") for (int n_ = 0; n_ < 4; ++n_) acc[m_][n_] = (f32x4){0.f, 0.f, 0.f, 0.f};

// ---------------- K1: trans_q = Q*W^T + b (fused split), split-store ----------------
// NO xcd_swz here: plain grid gives XCD x <-> W-panel nt=x (L2-resident) and
// mt (batch) round-robined across CUs -> seq_len imbalance averages out.
__global__ __launch_bounds__(256) void k_transq(const h16* __restrict__ Qhi,
                                                const h16* __restrict__ Qlo,
                                                const h16* __restrict__ Whi,
                                                const h16* __restrict__ Wlo,
                                                const float* __restrict__ bias,
                                                const int* __restrict__ seq,
                                                h16* __restrict__ Khi,
                                                h16* __restrict__ Klo) {
    int nt = blockIdx.x, mt = blockIdx.y;
    int b = mt >> 4;
    int q0 = (mt & 15) * 128;
    if (q0 >= seq[b]) return;
    __shared__ h16 lAh[128 * 64], lAl[128 * 64], lBh[128 * 64], lBl[128 * 64];
    ACC_INIT(acc);
    size_t aoff = (size_t)mt * 128 * HD;
    size_t boff = (size_t)nt * 128 * HD;
    gemm_split(Qhi + aoff, Qlo + aoff, HD, Whi + boff, Wlo + boff, HD, HD, acc,
               lAh, lAl, lBh, lBl);
    int lane = threadIdx.x & 63, wave = threadIdx.x >> 6;
    int wr = wave >> 1, wc = wave & 1, fr = lane & 15, fq = lane >> 4;
    size_t rowbase = (size_t)mt * 128;
#pragma unroll
    for (int m = 0; m < 4; ++m)
#pragma unroll
        for (int n = 0; n < 4; ++n) {
            int col = nt * 128 + wc * 64 + n * 16 + fr;
            float bv = bias[col];
#pragma unroll
            for (int j = 0; j < 4; ++j) {
                int row = wr * 64 + m * 16 + fq * 4 + j;
                float tv = acc[m][n][j] + bv;
                h16 th = (h16)tv;
                size_t idx = (rowbase + row) * HD + col;
                Khi[idx] = th;
                Klo[idx] = (h16)(tv - (float)th);
            }
        }
}

// ---------------- K2: S = P * K^T (fused split), f32 out ----------------
__global__ __launch_bounds__(256) void k_scores(const h16* __restrict__ Phi,
                                                const h16* __restrict__ Plo,
                                                const h16* __restrict__ Khi,
                                                const h16* __restrict__ Klo,
                                                const int* __restrict__ seq,
                                                float* __restrict__ S, int b0) {
    int qt, pt;
    xcd_swz(qt, pt);
    int lb = blockIdx.z;
    int b = b0 + lb;
    if (qt * 128 >= seq[b]) return;
    __shared__ h16 lAh[128 * 64], lAl[128 * 64], lBh[128 * 64], lBl[128 * 64];
    ACC_INIT(acc);
    size_t aoff = ((size_t)b * LP + pt * 128) * HD;
    size_t boff = ((size_t)b * LQS + qt * 128) * HD;
    gemm_split(Phi + aoff, Plo + aoff, HD, Khi + boff, Klo + boff, HD, HD, acc,
               lAh, lAl, lBh, lBl);
    int lane = threadIdx.x & 63, wave = threadIdx.x >> 6;
    int wr = wave >> 1, wc = wave & 1, fr = lane & 15, fq = lane >> 4;
    float* C = S + ((size_t)lb * LP + pt * 128) * LQS + qt * 128;
#pragma unroll
    for (int m = 0; m < 4; ++m)
#pragma unroll
        for (int n = 0; n < 4; ++n)
#pragma unroll
            for (int j = 0; j < 4; ++j) {
                int row = wr * 64 + m * 16 + fq * 4 + j;
                int col = wc * 64 + n * 16 + fr;
                C[(size_t)row * LQS + col] = acc[m][n][j];
            }
}

// ---------------- K3: softmax (reference mask/renorm semantics), PA f16 in-place ----------------
__global__ __launch_bounds__(256) void softmax_k(float* __restrict__ S,
                                                 const int* __restrict__ seq, int b0) {
    int wid = threadIdx.x >> 6, lane = threadIdx.x & 63;
    int r = blockIdx.x * 4 + wid;   // row within chunk [0, cb*LP)
    int b = b0 + (r >> 11);
    int L = seq[b];
    const float* Srow = S + (size_t)r * LQS;
    h16* Prow = (h16*)(S + (size_t)r * LQS);  // in-place: f16 writes trail f32 reads
    float m = -INFINITY;
    for (int i = lane; i < L; i += 64) m = fmaxf(m, Srow[i]);
#pragma unroll
    for (int off = 32; off; off >>= 1) m = fmaxf(m, __shfl_xor(m, off));
    float M = (L < LQS) ? fmaxf(m, 0.f) : m;
    float s = 0.f;
    for (int i = lane; i < L; i += 64) s += expf(Srow[i] - M);
#pragma unroll
    for (int off = 32; off; off >>= 1) s += __shfl_xor(s, off);
    float corr = (L < LQS) ? (float)(LQS - L) * expf(-M) : 0.f;
    float denom = s + 1e-13f * (s + corr);
    float inv = 1.f / denom;
    int Lpad = (L + 63) & ~63;
    for (int i = lane; i < L; i += 64) {
        float e = expf(Srow[i] - M) * inv;   // read (byte 4i) strictly leads write (byte 2i)
        Prow[i] = (h16)e;
    }
    for (int i = L + lane; i < Lpad; i += 64) Prow[i] = (h16)0.f;
}

// ---------------- K4: out = PA * VT^T ----------------
__global__ __launch_bounds__(256) void k_pv(const h16* __restrict__ PA,
                                            const h16* __restrict__ VT,
                                            const int* __restrict__ seq,
                                            float* __restrict__ out, int b0) {
    int ht, pt;
    xcd_swz(ht, pt);
    int lb = blockIdx.z;
    int b = b0 + lb;
    int L = seq[b];
    int Lpad = (L + 63) & ~63;
    __shared__ h16 ldsA[128 * 64], ldsB[128 * 64];
    ACC_INIT(acc);
    const h16* A0 = PA + ((size_t)lb * LP + pt * 128) * (2 * LQS);  // PA rows inside f32 S rows
    const h16* B0 = VT + ((size_t)b * HD + ht * 128) * LQS;
    gemm128(A0, 2 * LQS, B0, LQS, Lpad, acc, ldsA, ldsB);
    int lane = threadIdx.x & 63, wave = threadIdx.x >> 6;
    int wr = wave >> 1, wc = wave & 1, fr = lane & 15, fq = lane >> 4;
    float* C = out + ((size_t)b * LP + pt * 128) * HD + ht * 128;
#pragma unroll
    for (int m = 0; m < 4; ++m)
#pragma unroll
        for (int n = 0; n < 4; ++n)
#pragma unroll
            for (int j = 0; j < 4; ++j) {
                int row = wr * 64 + m * 16 + fq * 4 + j;
                int col = wc * 64 + n * 16 + fr;
                C[(size_t)row * HD + col] = acc[m][n][j];
            }
}

extern "C" void kernel_launch(void* const* d_in, const int* in_sizes, int n_in,
                              void* d_out, int out_size, void* d_ws, size_t ws_size,
                              hipStream_t stream) {
    const float* proj_p = (const float*)d_in[0];
    const float* proj_q = (const float*)d_in[1];
    const float* W_t    = (const float*)d_in[2];
    const float* b_t    = (const float*)d_in[3];
    const int*   seq    = (const int*)d_in[4];
    float* out = (float*)d_out;

    // Arena with phase-based reuse (persistent 160 MB + S chunk):
    //  [0,32M):    Qhi  -> (after transpose_v + cast) Phi
    //  [32M,64M):  Qlo  -> (after k_transq) VT
    //  [64M,96M):  Khi
    //  [96M,128M): Klo
    //  [128M,160M):Plo
    //  [160M,...): S chunk (cb batches x 16 MB, f32); Whi/Wlo live at 160M/162M
    //              during cast+k_transq only (dead before S written);
    //              PA = f16 rows written in-place over S rows by softmax_k.
    char* ws = (char*)d_ws;
    const size_t MB = (size_t)1 << 20;
    h16*  Qhi = (h16*)(ws + 0 * MB);
    h16*  Qlo = (h16*)(ws + 32 * MB);
    h16*  Khi = (h16*)(ws + 64 * MB);
    h16*  Klo = (h16*)(ws + 96 * MB);
    h16*  Plo = (h16*)(ws + 128 * MB);
    float* S  = (float*)(ws + 160 * MB);
    h16*  Whi = (h16*)(ws + 160 * MB);  // temporally overlapped with S
    h16*  Wlo = (h16*)(ws + 162 * MB);
    h16*  Phi = Qhi;                    // after transpose_v, Qhi reusable
    h16*  VT  = Qlo;                    // after k_transq, Qlo reusable
    const h16* PA = (const h16*)S;      // f16 rows in-place within f32 S rows
    (void)in_sizes; (void)n_in; (void)out_size;

    // Chunk batches so S fits in ws_size: need 160MB + cb*16MB.
    int cb = 8;
    if (ws_size > 0) {
        size_t avail = (ws_size > 160 * MB) ? (ws_size - 160 * MB) : 0;
        int fit = (int)(avail / (16 * MB));
        cb = (fit >= 8) ? 8 : (fit >= 4) ? 4 : (fit >= 2) ? 2 : 1;
    }

    cast_split<<<1024, 256, 0, stream>>>(W_t, Whi, Wlo, (long)HD * HD);
    cast_split<<<4096, 256, 0, stream>>>(proj_q, Qhi, Qlo, (long)NB * LQS * HD);
    k_transq<<<dim3(HD / 128, NB * LQS / 128), 256, 0, stream>>>(Qhi, Qlo, Whi, Wlo, b_t, seq, Khi, Klo);
    transpose_v<<<dim3(HD / 64, LQS / 64, NB), 256, 0, stream>>>(Qhi, VT);
    cast_split<<<4096, 256, 0, stream>>>(proj_p, Phi, Plo, (long)NB * LP * HD);
    for (int b0 = 0; b0 < NB; b0 += cb) {
        // same-stream ordering serializes chunk c's k_pv before chunk c+1's k_scores
        k_scores<<<dim3(LQS / 128, LP / 128, cb), 256, 0, stream>>>(Phi, Plo, Khi, Klo, seq, S, b0);
        softmax_k<<<cb * LP / 4, 256, 0, stream>>>(S, seq, b0);
        k_pv<<<dim3(HD / 128, LP / 128, cb), 256, 0, stream>>>(PA, VT, seq, out, b0);
    }
}